// Round 1
// baseline (286.327 us; speedup 1.0000x reference)
//
#include <hip/hip_runtime.h>
#include <hip/hip_bf16.h>

// Problem constants (from reference): B=16, N=128, H_DIM=128, E_DIM=64, M_DIM=128
#define NB 16
#define NN 128
#define HD 128
#define ED 64
#define MD 128

// ---------------------------------------------------------------------------
// Kernel 1: precompute hw1[b,n,m] = h[b,n,:]@W1[:,m]
//           and      t2pb[b,n,m] = h[b,n,:]@W2[:,m] + bias[m]
// Each block handles 8 flattened rows (b*N+n). 256 threads:
//   half 0 (tid 0..127)   -> W1 dots  -> hw1
//   half 1 (tid 128..255) -> W2 dots + bias -> t2pb
// ---------------------------------------------------------------------------
__global__ __launch_bounds__(256, 4) void prep_kernel(
    const float* __restrict__ h, const float* __restrict__ W,
    const float* __restrict__ bias,
    float* __restrict__ hw1, float* __restrict__ t2pb)
{
    __shared__ float hs[8][HD];
    const int tid  = threadIdx.x;
    const int row0 = blockIdx.x * 8;   // flattened b*N + n

    // stage 8 h-rows (8*128 floats) into LDS
    for (int t = tid; t < 8 * HD; t += 256) {
        hs[t >> 7][t & 127] = h[(size_t)row0 * HD + t];
    }
    __syncthreads();

    const int m    = tid & 127;
    const int half = tid >> 7;          // 0 -> W1, 1 -> W2
    const float* Wp = W + (size_t)half * HD * MD + m;

    float acc[8] = {0.f, 0.f, 0.f, 0.f, 0.f, 0.f, 0.f, 0.f};
#pragma unroll 4
    for (int d = 0; d < HD; ++d) {
        const float w = Wp[(size_t)d * MD];   // coalesced, L2-hot
#pragma unroll
        for (int r = 0; r < 8; ++r) acc[r] = fmaf(hs[r][d], w, acc[r]);
    }

    float* o = (half ? t2pb : hw1) + (size_t)row0 * MD + m;
    const float bb = half ? bias[m] : 0.f;
#pragma unroll
    for (int r = 0; r < 8; ++r) o[(size_t)r * MD] = acc[r] + bb;
}

// ---------------------------------------------------------------------------
// Kernel 2: one block per (b,i). 256 threads = 2 j-groups x 128 m-lanes.
//   out[b,i,j,m] = (hw1[b,j,m] + t2pb[b,i,m] + e[b,i,j,:]·W3[:,m]) * adj[b,i,j]
// W3 column kept in 64 VGPRs. e / adj addresses are wave-uniform -> scalar
// loads; adj==0 rows skip all compute (uniform branch) and store zeros.
// ---------------------------------------------------------------------------
__global__ __launch_bounds__(256, 4) void msg_kernel(
    const float* __restrict__ e, const float* __restrict__ adj,
    const float* __restrict__ W, const float* __restrict__ hw1,
    const float* __restrict__ t2pb, float* __restrict__ out)
{
    const int bx  = blockIdx.x;           // b*N + i
    const int tid = threadIdx.x;
    const int m   = tid & 127;
    // wave-uniform group index (waves 0,1 -> grp 0 ; waves 2,3 -> grp 1)
    const int grp = __builtin_amdgcn_readfirstlane(tid >> 7);

    // W3[:,m] into registers (W3 = W rows 256..319)
    float w3[ED];
    const float* W3p = W + (size_t)(2 * HD) * MD + m;
#pragma unroll
    for (int k = 0; k < ED; ++k) w3[k] = W3p[(size_t)k * MD];

    const float t2v = t2pb[(size_t)bx * MD + m];

    const float* __restrict__ ebase   = e   + (size_t)bx * NN * ED;
    const float* __restrict__ adjrow  = adj + (size_t)bx * NN;
    const float* __restrict__ hw1b    = hw1 + (size_t)(bx >> 7) * NN * MD; // b*N*MD
    float*       __restrict__ outbase = out + (size_t)bx * NN * MD;

    for (int jc = 0; jc < NN; jc += 8) {
        const int j0 = jc + grp * 4;
#pragma unroll
        for (int jj = 0; jj < 4; ++jj) {
            const int j = j0 + jj;
            const float adjv = adjrow[j];            // uniform -> s_load
            float* outrow = outbase + (size_t)j * MD;
            if (adjv != 0.f) {                       // wave-uniform branch
                const float* er = ebase + (size_t)j * ED;  // uniform addr
                float a0 = 0.f, a1 = 0.f, a2 = 0.f, a3 = 0.f;
#pragma unroll
                for (int k = 0; k < ED; k += 4) {
                    const float4 ev = *(const float4*)(er + k);  // s_load_dwordx4
                    a0 = fmaf(ev.x, w3[k + 0], a0);
                    a1 = fmaf(ev.y, w3[k + 1], a1);
                    a2 = fmaf(ev.z, w3[k + 2], a2);
                    a3 = fmaf(ev.w, w3[k + 3], a3);
                }
                const float r =
                    ((a0 + a1) + (a2 + a3) + hw1b[(size_t)j * MD + m] + t2v) * adjv;
                __builtin_nontemporal_store(r, outrow + m);
            } else {
                __builtin_nontemporal_store(0.f, outrow + m);
            }
        }
    }
}

// ---------------------------------------------------------------------------
extern "C" void kernel_launch(void* const* d_in, const int* in_sizes, int n_in,
                              void* d_out, int out_size, void* d_ws, size_t ws_size,
                              hipStream_t stream)
{
    const float* h    = (const float*)d_in[0];
    const float* e    = (const float*)d_in[1];
    const float* adj  = (const float*)d_in[2];
    const float* W    = (const float*)d_in[3];
    const float* bias = (const float*)d_in[4];
    float* out = (float*)d_out;

    float* hw1  = (float*)d_ws;                       // (B*N, MD) = 1 MB
    float* t2pb = hw1 + (size_t)NB * NN * MD;         // (B*N, MD) = 1 MB

    // kernel 1: 2048 rows / 8 per block = 256 blocks
    prep_kernel<<<dim3((NB * NN) / 8), dim3(256), 0, stream>>>(h, W, bias, hw1, t2pb);

    // kernel 2: one block per (b,i) = 2048 blocks
    msg_kernel<<<dim3(NB * NN), dim3(256), 0, stream>>>(e, adj, W, hw1, t2pb, out);
}

// Round 4
// 271.111 us; speedup vs baseline: 1.0561x; 1.0561x over previous
//
#include <hip/hip_runtime.h>
#include <hip/hip_bf16.h>

// Problem constants: B=16, N=128, H_DIM=128, E_DIM=64, M_DIM=128
#define NB 16
#define NN 128
#define HD 128
#define ED 64
#define MD 128

// ---------------------------------------------------------------------------
// Kernel 1: one block per flattened row (b*N+n), 128 threads (thread = m).
//   hw1[row,m]  = h[row,:]@W1[:,m]
//   t2pb[row,m] = h[row,:]@W2[:,m] + bias[m]
// h row staged in LDS (broadcast reads); W reads coalesced across m, L2-hot.
// 2048 blocks -> 8 blocks/CU -> latency well hidden.
// ---------------------------------------------------------------------------
__global__ __launch_bounds__(128, 8) void prep_kernel(
    const float* __restrict__ h, const float* __restrict__ W,
    const float* __restrict__ bias,
    float* __restrict__ hw1, float* __restrict__ t2pb)
{
    __shared__ float hs[HD];
    const int row = blockIdx.x;          // b*N + n
    const int m   = threadIdx.x;         // 0..127

    hs[m] = h[(size_t)row * HD + m];
    __syncthreads();

    float a1 = 0.f, a2 = 0.f;
    const float* W1p = W + m;                      // W rows 0..127
    const float* W2p = W + (size_t)HD * MD + m;    // W rows 128..255
#pragma unroll 8
    for (int d = 0; d < HD; ++d) {
        const float hv = hs[d];                    // uniform -> broadcast
        a1 = fmaf(hv, W1p[(size_t)d * MD], a1);
        a2 = fmaf(hv, W2p[(size_t)d * MD], a2);
    }
    hw1 [(size_t)row * MD + m] = a1;
    t2pb[(size_t)row * MD + m] = a2 + bias[m];
}

// ---------------------------------------------------------------------------
// Kernel 2: one block per (b,i), 256 threads = 4 waves.
// Lane = j (per-lane data), m = uniform loop index:
//   wave 0: j in [0,64),   m in [0,64)      wave 1: j in [64,128), m in [0,64)
//   wave 2: j in [0,64),   m in [64,128)    wave 3: j in [64,128), m in [64,128)
// e[b,i,:,:] staged coalesced into LDS (pad 68 floats/row).
// W3[k][m] is wave-uniform -> scalar loads feed v_fmac's SGPR operand.
// Dense compute; adj applied at the coalesced store phase after an LDS
// transpose (acc -> tbuf[64][129], +1 pad => conflict-free).
// ---------------------------------------------------------------------------
__global__ __launch_bounds__(256, 4) void msg_kernel(
    const float* __restrict__ e, const float* __restrict__ adj,
    const float* __restrict__ W, const float* __restrict__ hw1,
    const float* __restrict__ t2pb, float* __restrict__ out)
{
    __shared__ float elds[NN][ED + 4];   // 128 x 68 floats = 34816 B

    const int bx   = blockIdx.x;                 // b*N + i
    const int tid  = threadIdx.x;
    const int wave = __builtin_amdgcn_readfirstlane(tid >> 6);  // uniform!
    const int lane = tid & 63;

    const float* __restrict__ ebase = e + (size_t)bx * NN * ED;

    // ---- stage e[b,i,:,:] coalesced: 2048 float4 / 256 threads = 8 each
    for (int t = tid; t < NN * ED / 4; t += 256) {
        const float4 v = ((const float4*)ebase)[t];
        const int j = t >> 4;              // (t*4)/64
        const int k = (t & 15) * 4;
        *(float4*)&elds[j][k] = v;         // row stride 272B, k*4 mult of 16
    }
    __syncthreads();

    const int jbase = (wave & 1) * 64;
    const int mbase = (wave >> 1) * 64;    // uniform
    const int j     = jbase + lane;

    const float* __restrict__ W3r = W + (size_t)(2 * HD) * MD + mbase; // uniform

    float acc[64];
#pragma unroll
    for (int m = 0; m < 64; ++m) acc[m] = 0.f;

    // ---- dense e.W3: per lane 64k x 64m FMAs, W3 via scalar pipe
    for (int k4 = 0; k4 < ED; k4 += 4) {
        const float4 ev = *(const float4*)&elds[j][k4];   // ds_read_b128
#pragma unroll
        for (int kk = 0; kk < 4; ++kk) {
            const float* __restrict__ wrow = W3r + (size_t)(k4 + kk) * MD; // uniform
            const float evk = (&ev.x)[kk];
#pragma unroll
            for (int m = 0; m < 64; ++m)
                acc[m] = fmaf(evk, wrow[m], acc[m]);      // v_fmac v, s, v
        }
    }

    // ---- store: transpose acc through LDS (reuse e buffer), fuse adds+adj
    float* tbuf = &elds[0][0];             // 64*129 = 8256 floats <= 8704
    const float* __restrict__ adjrow   = adj  + (size_t)bx * NN;
    const float* __restrict__ hw1b     = hw1  + (size_t)(bx >> 7) * NN * MD;
    const float* __restrict__ t2row    = t2pb + (size_t)bx * MD;
    float*       __restrict__ outbase  = out  + (size_t)bx * NN * MD;

#pragma unroll
    for (int h = 0; h < 2; ++h) {          // j-half h covers j in [h*64,(h+1)*64)
        __syncthreads();                    // elds free / previous stores done
        if ((wave & 1) == h) {
#pragma unroll
            for (int m = 0; m < 64; ++m)
                tbuf[lane * 129 + mbase + m] = acc[m];   // 2-way free
        }
        __syncthreads();
        for (int t = tid; t < 64 * MD; t += 256) {
            const int jl = __builtin_amdgcn_readfirstlane(t >> 7); // uniform/wave
            const int m  = t & 127;
            const int jg = h * 64 + jl;
            const float r = (tbuf[jl * 129 + m]
                             + hw1b[(size_t)jg * MD + m]
                             + t2row[m]) * adjrow[jg];
            __builtin_nontemporal_store(r, outbase + (size_t)jg * MD + m);
        }
    }
}

// ---------------------------------------------------------------------------
extern "C" void kernel_launch(void* const* d_in, const int* in_sizes, int n_in,
                              void* d_out, int out_size, void* d_ws, size_t ws_size,
                              hipStream_t stream)
{
    const float* h    = (const float*)d_in[0];
    const float* e    = (const float*)d_in[1];
    const float* adj  = (const float*)d_in[2];
    const float* W    = (const float*)d_in[3];
    const float* bias = (const float*)d_in[4];
    float* out = (float*)d_out;

    float* hw1  = (float*)d_ws;                       // (B*N, MD) = 1 MB
    float* t2pb = hw1 + (size_t)NB * NN * MD;         // (B*N, MD) = 1 MB

    prep_kernel<<<dim3(NB * NN), dim3(128), 0, stream>>>(h, W, bias, hw1, t2pb);
    msg_kernel <<<dim3(NB * NN), dim3(256), 0, stream>>>(e, adj, W, hw1, t2pb, out);
}

// Round 6
// 239.013 us; speedup vs baseline: 1.1980x; 1.1343x over previous
//
#include <hip/hip_runtime.h>
#include <hip/hip_bf16.h>

// Problem constants: B=16, N=128, H_DIM=128, E_DIM=64, M_DIM=128
#define NB 16
#define NN 128
#define HD 128
#define ED 64
#define MD 128

typedef float f32x4 __attribute__((ext_vector_type(4)));

// ---------------------------------------------------------------------------
// Kernel 1 (verified round-1): one block per row (b*N+n), 128 threads (= m).
//   hw1[row,m]  = h[row,:]@W1[:,m]
//   t2pb[row,m] = h[row,:]@W2[:,m] + bias[m]
// ---------------------------------------------------------------------------
__global__ __launch_bounds__(128, 8) void prep_kernel(
    const float* __restrict__ h, const float* __restrict__ W,
    const float* __restrict__ bias,
    float* __restrict__ hw1, float* __restrict__ t2pb)
{
    __shared__ float hs[HD];
    const int row = blockIdx.x;          // b*N + n
    const int m   = threadIdx.x;         // 0..127

    hs[m] = h[(size_t)row * HD + m];
    __syncthreads();

    float a1 = 0.f, a2 = 0.f;
    const float* W1p = W + m;                      // W rows 0..127
    const float* W2p = W + (size_t)HD * MD + m;    // W rows 128..255
#pragma unroll 8
    for (int d = 0; d < HD; ++d) {
        const float hv = hs[d];                    // uniform -> broadcast
        a1 = fmaf(hv, W1p[(size_t)d * MD], a1);
        a2 = fmaf(hv, W2p[(size_t)d * MD], a2);
    }
    hw1 [(size_t)row * MD + m] = a1;
    t2pb[(size_t)row * MD + m] = a2 + bias[m];
}

// ---------------------------------------------------------------------------
// Kernel 2: one block per (b,i), 512 threads = 8 waves = (j-half, m-quarter).
//   wave w: jhalf = w&1 (lane = local j), m-quarter mq4 = w>>1 (32 m's, acc[32])
// LDS (exactly 64 KB):
//   smem[0..8191]     : e[b,i] as 2048 float4-quads, quad-swizzled q^=(j&7)
//   smem[8192..16383] : W3[64][128] linear; reused as tbuf[64][32quads]
//                       (quad-swizzled) in the store phase.
// Hot loop has NO smem/global ops -> fine-grained lgkmcnt pipelining of
// ds_read under v_fmac. W3 reads are uniform-address (broadcast).
// ---------------------------------------------------------------------------
__global__ __launch_bounds__(512, 4) void msg_kernel(
    const float* __restrict__ e, const float* __restrict__ adj,
    const float* __restrict__ W, const float* __restrict__ hw1,
    const float* __restrict__ t2pb, float* __restrict__ out)
{
    __shared__ float smem[16384];                     // 65536 B
    float4* __restrict__ eq = (float4*)smem;          // 2048 quads (e, swizzled)
    float4* __restrict__ wq = (float4*)(smem + 8192); // 2048 quads (W3, linear)

    const int bx   = blockIdx.x;                      // b*N + i
    const int tid  = threadIdx.x;
    const int w    = __builtin_amdgcn_readfirstlane(tid >> 6);  // wave id 0..7
    const int lane = tid & 63;

    const float4* __restrict__ e4  = (const float4*)(e + (size_t)bx * NN * ED);
    const float4* __restrict__ W3q = (const float4*)(W + (size_t)(2 * HD) * MD);

    // ---- stage e (quad-swizzled) and W3 (linear): 2048 quads each
#pragma unroll
    for (int it = 0; it < 4; ++it) {
        const int idx = tid + it * 512;       // 0..2047
        const int j   = idx >> 4;             // e row
        const int kq  = idx & 15;             // k-quad within row
        eq[16 * j + (kq ^ (j & 7))] = e4[idx];
        wq[idx] = W3q[idx];
    }
    __syncthreads();

    const int jhalf = w & 1;
    const int mq4   = w >> 1;                 // 0..3 -> m in [32*mq4, 32*mq4+32)
    const int j     = jhalf * 64 + lane;
    const int jx    = j & 7;
    const int ebase = 16 * j;                 // quad base of row j
    const int wbase = 8 * mq4;                // quad offset inside a W3 k-row

    float acc[32];
#pragma unroll
    for (int i = 0; i < 32; ++i) acc[i] = 0.f;

    // ---- e.W3: per k: 1 per-lane ev component, 8 uniform wv quads, 32 FMA
#pragma unroll 2
    for (int q = 0; q < 16; ++q) {
        const float4 ev = eq[ebase + (q ^ jx)];       // e[j][4q..4q+3]
#pragma unroll
        for (int kk = 0; kk < 4; ++kk) {
            const float evk = (kk == 0) ? ev.x : (kk == 1) ? ev.y
                             : (kk == 2) ? ev.z : ev.w;
            const float4* __restrict__ wrow = wq + 32 * (4 * q + kk) + wbase; // uniform
#pragma unroll
            for (int p = 0; p < 8; ++p) {
                const float4 wv = wrow[p];            // broadcast ds_read_b128
                acc[4 * p + 0] = fmaf(evk, wv.x, acc[4 * p + 0]);
                acc[4 * p + 1] = fmaf(evk, wv.y, acc[4 * p + 1]);
                acc[4 * p + 2] = fmaf(evk, wv.z, acc[4 * p + 2]);
                acc[4 * p + 3] = fmaf(evk, wv.w, acc[4 * p + 3]);
            }
        }
    }

    // ---- store: transpose via tbuf (overlays W3 region), fuse adds + adj
    float4* __restrict__ tq = wq;             // 64 rows x 32 quads, swizzled
    const float*  __restrict__ adjrow = adj  + (size_t)bx * NN;
    const float4* __restrict__ hw1b   = (const float4*)(hw1 + (size_t)(bx >> 7) * NN * MD);
    const float4* __restrict__ t2row  = (const float4*)(t2pb + (size_t)bx * MD);
    f32x4*        __restrict__ outb   = (f32x4*)(out + (size_t)bx * NN * MD);

#pragma unroll
    for (int h = 0; h < 2; ++h) {
        __syncthreads();                      // k-loop (h=0) / prev stores (h=1) done
        if (jhalf == h) {
            const int lx = lane & 7;
#pragma unroll
            for (int p = 0; p < 8; ++p) {
                const int qm = wbase + p;     // quad 0..31 within row; qm&7 == p
                tq[32 * lane + (qm ^ lx)] =
                    make_float4(acc[4 * p + 0], acc[4 * p + 1],
                                acc[4 * p + 2], acc[4 * p + 3]);
            }
        }
        __syncthreads();
#pragma unroll
        for (int it = 0; it < 4; ++it) {
            const int t4 = tid + it * 512;    // 0..2047 quads of this j-half
            const int jl = t4 >> 5;           // 0..63 local row
            const int mq = t4 & 31;           // quad in row
            const int jg = h * 64 + jl;
            const float4 v  = tq[32 * jl + (mq ^ (jl & 7))];
            const float4 h1 = hw1b[(size_t)jg * 32 + mq];
            const float4 t2 = t2row[mq];
            const float  a  = adjrow[jg];
            f32x4 r;
            r.x = (v.x + h1.x + t2.x) * a;
            r.y = (v.y + h1.y + t2.y) * a;
            r.z = (v.z + h1.z + t2.z) * a;
            r.w = (v.w + h1.w + t2.w) * a;
            __builtin_nontemporal_store(r, outb + (size_t)jg * 32 + mq);
        }
    }
}

// ---------------------------------------------------------------------------
extern "C" void kernel_launch(void* const* d_in, const int* in_sizes, int n_in,
                              void* d_out, int out_size, void* d_ws, size_t ws_size,
                              hipStream_t stream)
{
    const float* h    = (const float*)d_in[0];
    const float* e    = (const float*)d_in[1];
    const float* adj  = (const float*)d_in[2];
    const float* W    = (const float*)d_in[3];
    const float* bias = (const float*)d_in[4];
    float* out = (float*)d_out;

    float* hw1  = (float*)d_ws;                       // (B*N, MD) = 1 MB
    float* t2pb = hw1 + (size_t)NB * NN * MD;         // (B*N, MD) = 1 MB

    prep_kernel<<<dim3(NB * NN), dim3(128), 0, stream>>>(h, W, bias, hw1, t2pb);
    msg_kernel <<<dim3(NB * NN), dim3(512), 0, stream>>>(e, adj, W, hw1, t2pb, out);
}